// Round 12
// baseline (252.209 us; speedup 1.0000x reference)
//
#include <hip/hip_runtime.h>

#define N_NODES 100000
#define N_EDGES 1600000
#define D 128           // D_IN == D_OUT == 128
#define D4 32           // D in float4 units

#define BM 128                                   // gemm rows per block
#define GEMM_BLOCKS ((N_NODES + BM - 1) / BM)    // 782
#define FILL_BLOCKS 256                          // edge-fill blocks (dispatch first)
#define TOTAL_BLOCKS (FILL_BLOCKS + GEMM_BLOCKS)
#define LDK 136                                  // padded LDS row (bf16 elems)

#define BK 32                                    // nodes per bucket
#define NBUCKETS (N_NODES / BK)                  // 3125 exactly
#define CAPB 1024                                // slots per bucket (22 sigma)
#define SPILL_CAP 32768

typedef __attribute__((ext_vector_type(8))) short short8;   // MFMA A/B frag
typedef __attribute__((ext_vector_type(4))) float floatx4;  // MFMA C/D frag

// ---- bf16 helpers ----------------------------------------------------------
__device__ __forceinline__ unsigned short f2bf(float f) {
    unsigned int b = __float_as_uint(f);
    b += 0x7FFFu + ((b >> 16) & 1u);           // RNE
    return (unsigned short)(b >> 16);
}
__device__ __forceinline__ float bf2f(unsigned short u) {
    return __uint_as_float((unsigned int)u << 16);
}

// ---------------------------------------------------------------------------
// W^T prep (once): wt[n*128+k] = bf16(W[k*128+n]).
// ---------------------------------------------------------------------------
__global__ __launch_bounds__(256) void w_prep(
    const float* __restrict__ W, unsigned short* __restrict__ wt)
{
    int idx = blockIdx.x * 256 + threadIdx.x;   // 0..16383
    int k = idx >> 7, n = idx & 127;
    wt[(size_t)n * D + k] = f2bf(W[idx]);
}

// ---------------------------------------------------------------------------
// Mega kernel, block-specialized:
//   blocks [0, FILL_BLOCKS): bucket fill — pos = atomicAdd(len[b]),
//     pairs[b*CAPB+pos] = {col | local<<17, w_bits}. Sequential-in-bucket
//     writes (no line amp); overflow -> spill list (normally empty).
//   blocks [FILL_BLOCKS, ...): MFMA GEMM tile (proven R10/R11 structure).
// ---------------------------------------------------------------------------
__global__ __launch_bounds__(256, 4) void mega(
    const float* __restrict__ x, const unsigned short* __restrict__ wt,
    unsigned short* __restrict__ sup,
    const int* __restrict__ row, const int* __restrict__ col,
    const float* __restrict__ ew,
    int* __restrict__ len, int2* __restrict__ pairs,
    int* __restrict__ spill_cnt, int4* __restrict__ spill)
{
    __shared__ unsigned short xs[BM * LDK];      // 34.0 KB (gemm path only)

    const int tid = threadIdx.x;

    if (blockIdx.x < FILL_BLOCKS) {
        for (int e = blockIdx.x * 256 + tid; e < N_EDGES; e += FILL_BLOCKS * 256) {
            int r = row[e];
            int b = r >> 5;
            int packed = col[e] | ((r & 31) << 17);
            int wb = __float_as_int(ew[e]);
            int pos = atomicAdd(&len[b], 1);
            if (pos < CAPB) {
                pairs[(size_t)b * CAPB + pos] = make_int2(packed, wb);
            } else {
                int si = atomicAdd(spill_cnt, 1);
                if (si < SPILL_CAP) spill[si] = make_int4(b, packed, wb, 0);
            }
        }
        return;
    }

    // ---- GEMM path
    const int brow = (blockIdx.x - FILL_BLOCKS) * BM;

    {
        const float4* xv = reinterpret_cast<const float4*>(x);
        #pragma unroll
        for (int i = 0; i < 16; ++i) {
            int idx = tid + i * 256;             // 0..4095
            int r = idx >> 5, k4 = idx & 31;
            int gr = brow + r;
            float4 v = (gr < N_NODES) ? xv[(size_t)gr * D4 + k4]
                                      : make_float4(0.f, 0.f, 0.f, 0.f);
            ushort4 p;
            p.x = f2bf(v.x); p.y = f2bf(v.y); p.z = f2bf(v.z); p.w = f2bf(v.w);
            *reinterpret_cast<ushort4*>(&xs[r * LDK + k4 * 4]) = p;
        }
    }
    __syncthreads();

    const int wave = tid >> 6;
    const int lane = tid & 63;
    const int l15  = lane & 15;
    const int lkg  = lane >> 4;                  // 0..3

    floatx4 acc[2][8];
    #pragma unroll
    for (int m = 0; m < 2; ++m)
        #pragma unroll
        for (int n = 0; n < 8; ++n) acc[m][n] = (floatx4){0.f, 0.f, 0.f, 0.f};

    const short8* bv = reinterpret_cast<const short8*>(wt);
    const int wrow = wave * 32;
    #pragma unroll
    for (int kk = 0; kk < 4; ++kk) {
        int kb = kk * 32 + lkg * 8;
        short8 a0 = *reinterpret_cast<const short8*>(&xs[(wrow + l15) * LDK + kb]);
        short8 a1 = *reinterpret_cast<const short8*>(&xs[(wrow + 16 + l15) * LDK + kb]);
        #pragma unroll
        for (int n = 0; n < 8; ++n) {
            short8 b = bv[(n * 16 + l15) * 16 + kk * 4 + lkg];
            acc[0][n] = __builtin_amdgcn_mfma_f32_16x16x32_bf16(a0, b, acc[0][n], 0, 0, 0);
            acc[1][n] = __builtin_amdgcn_mfma_f32_16x16x32_bf16(a1, b, acc[1][n], 0, 0, 0);
        }
    }

    const int rbase = brow + wrow + lkg * 4;
    #pragma unroll
    for (int m = 0; m < 2; ++m) {
        #pragma unroll
        for (int r = 0; r < 4; ++r) {
            int grow = rbase + m * 16 + r;
            if (grow < N_NODES) {
                #pragma unroll
                for (int n = 0; n < 8; ++n)
                    sup[(size_t)grow * D + n * 16 + l15] = f2bf(acc[m][n][r]);
            }
        }
    }
}

// ---------------------------------------------------------------------------
// Gather: one block per bucket (32 nodes). Sequential pair reads -> LDS
// counting-sort by node-local id (native int ds_add) -> each half-wave
// processes its 4 nodes' dense runs with unroll-4 support loads.
// ---------------------------------------------------------------------------
__global__ __launch_bounds__(256) void gather_bucket(
    const int* __restrict__ len, const int2* __restrict__ pairs,
    const int* __restrict__ spill_cnt, const int4* __restrict__ spill,
    const unsigned short* __restrict__ sup, float* __restrict__ out)
{
    __shared__ int2 sorted[CAPB];                // 8 KB
    __shared__ int bins[BK];
    __shared__ int boffs[BK + 1];
    __shared__ int bcur[BK];

    const int b = blockIdx.x;
    const int tid = threadIdx.x;
    const int cnt = len[b];
    const int cl = cnt < CAPB ? cnt : CAPB;
    const int2* pp = pairs + (size_t)b * CAPB;

    if (tid < BK) bins[tid] = 0;
    __syncthreads();

    // pass 1: count per-node
    for (int i = tid; i < cl; i += 256)
        atomicAdd(&bins[pp[i].x >> 17], 1);
    __syncthreads();

    // tiny serial scan of 32 bins
    if (tid == 0) {
        int s = 0;
        #pragma unroll
        for (int j = 0; j < BK; ++j) { boffs[j] = s; bcur[j] = s; s += bins[j]; }
        boffs[BK] = s;
    }
    __syncthreads();

    // pass 2: scatter into sorted (LDS scatter, no line amp)
    for (int i = tid; i < cl; i += 256) {
        int2 p = pp[i];
        int pos = atomicAdd(&bcur[p.x >> 17], 1);
        sorted[pos] = p;
    }
    __syncthreads();

    const int half = tid >> 5;                   // 0..7
    const int lane = tid & 31;
    const int sc = *spill_cnt;                   // normally 0
    const ushort4* supv = reinterpret_cast<const ushort4*>(sup);
    float4* ov = reinterpret_cast<float4*>(out);

    #pragma unroll
    for (int j = 0; j < 4; ++j) {
        const int loc = half * 4 + j;
        const int s0 = boffs[loc], s1 = boffs[loc + 1];
        float4 a = {0.f, 0.f, 0.f, 0.f};

        int k = s0;
        for (; k + 4 <= s1; k += 4) {
            int2 p0 = sorted[k], p1 = sorted[k + 1];
            int2 p2 = sorted[k + 2], p3 = sorted[k + 3];
            ushort4 q0 = supv[(size_t)(p0.x & 0x1FFFF) * D4 + lane];
            ushort4 q1 = supv[(size_t)(p1.x & 0x1FFFF) * D4 + lane];
            ushort4 q2 = supv[(size_t)(p2.x & 0x1FFFF) * D4 + lane];
            ushort4 q3 = supv[(size_t)(p3.x & 0x1FFFF) * D4 + lane];
            float w0 = __int_as_float(p0.y), w1 = __int_as_float(p1.y);
            float w2 = __int_as_float(p2.y), w3 = __int_as_float(p3.y);
            a.x = fmaf(w0, bf2f(q0.x), a.x); a.y = fmaf(w0, bf2f(q0.y), a.y);
            a.z = fmaf(w0, bf2f(q0.z), a.z); a.w = fmaf(w0, bf2f(q0.w), a.w);
            a.x = fmaf(w1, bf2f(q1.x), a.x); a.y = fmaf(w1, bf2f(q1.y), a.y);
            a.z = fmaf(w1, bf2f(q1.z), a.z); a.w = fmaf(w1, bf2f(q1.w), a.w);
            a.x = fmaf(w2, bf2f(q2.x), a.x); a.y = fmaf(w2, bf2f(q2.y), a.y);
            a.z = fmaf(w2, bf2f(q2.z), a.z); a.w = fmaf(w2, bf2f(q2.w), a.w);
            a.x = fmaf(w3, bf2f(q3.x), a.x); a.y = fmaf(w3, bf2f(q3.y), a.y);
            a.z = fmaf(w3, bf2f(q3.z), a.z); a.w = fmaf(w3, bf2f(q3.w), a.w);
        }
        for (; k < s1; ++k) {
            int2 p = sorted[k];
            ushort4 q = supv[(size_t)(p.x & 0x1FFFF) * D4 + lane];
            float w = __int_as_float(p.y);
            a.x = fmaf(w, bf2f(q.x), a.x); a.y = fmaf(w, bf2f(q.y), a.y);
            a.z = fmaf(w, bf2f(q.z), a.z); a.w = fmaf(w, bf2f(q.w), a.w);
        }

        // spill safety net (sc == 0 in practice)
        for (int i2 = 0; i2 < sc; ++i2) {
            int4 sp = spill[i2];
            if (sp.x == b && (sp.y >> 17) == loc) {
                ushort4 q = supv[(size_t)(sp.y & 0x1FFFF) * D4 + lane];
                float w = __int_as_float(sp.z);
                a.x = fmaf(w, bf2f(q.x), a.x); a.y = fmaf(w, bf2f(q.y), a.y);
                a.z = fmaf(w, bf2f(q.z), a.z); a.w = fmaf(w, bf2f(q.w), a.w);
            }
        }

        ov[(size_t)(b * BK + loc) * D4 + lane] = a;
    }
}

// ---------------------------------------------------------------------------
// Fallback path (ws too small): VALU gemm + atomic scatter (proven R3/R8).
// ---------------------------------------------------------------------------
__device__ __forceinline__ void fma4(float4& a, float s, const float4& b) {
    a.x = fmaf(s, b.x, a.x);
    a.y = fmaf(s, b.y, a.y);
    a.z = fmaf(s, b.z, a.z);
    a.w = fmaf(s, b.w, a.w);
}

__global__ __launch_bounds__(256) void gemm_xw(
    const float* __restrict__ x, const float* __restrict__ W,
    unsigned short* __restrict__ sup)
{
    __shared__ float4 xs[32 * D4];
    const int tid = threadIdx.x;
    const int block_row = blockIdx.x * 32;

    const float4* xv = reinterpret_cast<const float4*>(x) + (size_t)block_row * D4;
    #pragma unroll
    for (int i = 0; i < 4; ++i) xs[tid + i * 256] = xv[tid + i * 256];
    __syncthreads();

    const int cg = tid & 31;
    const int rg = tid >> 5;
    const float4* Wv = reinterpret_cast<const float4*>(W);

    float4 acc0 = {0.f, 0.f, 0.f, 0.f};
    float4 acc1 = acc0, acc2 = acc0, acc3 = acc0;

    const int r0 = rg * 4;
    #pragma unroll 8
    for (int k4 = 0; k4 < D4; ++k4) {
        float4 xa = xs[(r0 + 0) * D4 + k4];
        float4 xb = xs[(r0 + 1) * D4 + k4];
        float4 xc = xs[(r0 + 2) * D4 + k4];
        float4 xd = xs[(r0 + 3) * D4 + k4];
        float4 w0 = Wv[(k4 * 4 + 0) * D4 + cg];
        fma4(acc0, xa.x, w0); fma4(acc1, xb.x, w0);
        fma4(acc2, xc.x, w0); fma4(acc3, xd.x, w0);
        float4 w1 = Wv[(k4 * 4 + 1) * D4 + cg];
        fma4(acc0, xa.y, w1); fma4(acc1, xb.y, w1);
        fma4(acc2, xc.y, w1); fma4(acc3, xd.y, w1);
        float4 w2 = Wv[(k4 * 4 + 2) * D4 + cg];
        fma4(acc0, xa.z, w2); fma4(acc1, xb.z, w2);
        fma4(acc2, xc.z, w2); fma4(acc3, xd.z, w2);
        float4 w3 = Wv[(k4 * 4 + 3) * D4 + cg];
        fma4(acc0, xa.w, w3); fma4(acc1, xb.w, w3);
        fma4(acc2, xc.w, w3); fma4(acc3, xd.w, w3);
    }

    ushort4 p;
    #define STORE_BF16(ACC, R)                                            \
        p.x = f2bf(ACC.x); p.y = f2bf(ACC.y);                             \
        p.z = f2bf(ACC.z); p.w = f2bf(ACC.w);                             \
        *reinterpret_cast<ushort4*>(sup + (size_t)(block_row + r0 + R) * D + cg * 4) = p;
    STORE_BF16(acc0, 0)
    STORE_BF16(acc1, 1)
    STORE_BF16(acc2, 2)
    STORE_BF16(acc3, 3)
    #undef STORE_BF16
}

__global__ __launch_bounds__(256) void scatter_edges(
    const int* __restrict__ row, const int* __restrict__ col,
    const float* __restrict__ ew, const unsigned short* __restrict__ sup,
    float* __restrict__ out)
{
    const int e = blockIdx.x * 8 + (threadIdx.x >> 5);
    if (e >= N_EDGES) return;
    const int lane = threadIdx.x & 31;

    const int r = row[e];
    const int c = col[e];
    const float w = ew[e];
    ushort4 s = reinterpret_cast<const ushort4*>(sup + (size_t)c * D)[lane];
    float* o = out + (size_t)r * D + lane * 4;
    atomicAdd(o + 0, w * bf2f(s.x));
    atomicAdd(o + 1, w * bf2f(s.y));
    atomicAdd(o + 2, w * bf2f(s.z));
    atomicAdd(o + 3, w * bf2f(s.w));
}

extern "C" void kernel_launch(void* const* d_in, const int* in_sizes, int n_in,
                              void* d_out, int out_size, void* d_ws, size_t ws_size,
                              hipStream_t stream)
{
    const float* x      = (const float*)d_in[0];   // [N_NODES, 128]
    const int*   row    = (const int*)d_in[1];     // [N_EDGES]
    const int*   col    = (const int*)d_in[2];     // [N_EDGES]
    const float* ew     = (const float*)d_in[3];   // [N_EDGES]
    const float* weight = (const float*)d_in[4];   // [128, 128]
    float* out = (float*)d_out;                    // [N_NODES, 128]

    char* ws = (char*)d_ws;
    const size_t off_sup    = 0;                                        // 25.6 MB
    const size_t off_pairs  = off_sup + (size_t)N_NODES * D * 2;        // 25.6 MB
    const size_t off_len    = off_pairs + (size_t)NBUCKETS * CAPB * 8;  // 12.5 KB
    const size_t off_wt     = off_len + (size_t)NBUCKETS * 4;           // 32 KB
    const size_t off_scnt   = off_wt + (size_t)D * D * 2;               // 16 B
    const size_t off_spill  = off_scnt + 16;                            // 512 KB
    const size_t required   = off_spill + (size_t)SPILL_CAP * 16;

    unsigned short* sup = (unsigned short*)(ws + off_sup);

    if (ws_size >= required) {
        int2* pairs = (int2*)(ws + off_pairs);
        int*  len   = (int*)(ws + off_len);
        unsigned short* wt = (unsigned short*)(ws + off_wt);
        int*  scnt  = (int*)(ws + off_scnt);
        int4* spill = (int4*)(ws + off_spill);

        hipMemsetAsync(len, 0, (size_t)NBUCKETS * 4, stream);
        hipMemsetAsync(scnt, 0, 16, stream);
        w_prep<<<D * D / 256, 256, 0, stream>>>(weight, wt);

        // block-specialized: fill (first) + MFMA gemm tiles, overlapped
        mega<<<TOTAL_BLOCKS, 256, 0, stream>>>(
            x, wt, sup, row, col, ew, len, pairs, scnt, spill);

        // gather: one block per bucket, writes every output row
        gather_bucket<<<NBUCKETS, 256, 0, stream>>>(
            len, pairs, scnt, spill, sup, out);
    } else {
        gemm_xw<<<N_NODES / 32, 256, 0, stream>>>(x, weight, sup);
        hipMemsetAsync(d_out, 0, (size_t)N_NODES * D * sizeof(float), stream);
        scatter_edges<<<N_EDGES / 8, 256, 0, stream>>>(row, col, ew, sup, out);
    }
}

// Round 13
// 195.403 us; speedup vs baseline: 1.2907x; 1.2907x over previous
//
#include <hip/hip_runtime.h>

#define N_NODES 100000
#define N_EDGES 1600000
#define D 128           // D_IN == D_OUT == 128
#define D4 32           // D in float4 units

#define BM 128                                   // gemm rows per block
#define GEMM_BLOCKS ((N_NODES + BM - 1) / BM)    // 782
#define BUILD_BLOCKS 256                         // edge-list builder blocks
#define TOTAL_BLOCKS (BUILD_BLOCKS + GEMM_BLOCKS)
#define LDK 136                                  // padded LDS row (bf16 elems)

typedef __attribute__((ext_vector_type(8))) short short8;   // MFMA A/B frag
typedef __attribute__((ext_vector_type(4))) float floatx4;  // MFMA C/D frag

// ---- bf16 helpers ----------------------------------------------------------
__device__ __forceinline__ unsigned short f2bf(float f) {
    unsigned int b = __float_as_uint(f);
    b += 0x7FFFu + ((b >> 16) & 1u);           // RNE
    return (unsigned short)(b >> 16);
}
__device__ __forceinline__ float bf2f(unsigned short u) {
    return __uint_as_float((unsigned int)u << 16);
}

// ---------------------------------------------------------------------------
// W^T prep (once): wt[n*128+k] = bf16(W[k*128+n]).
// ---------------------------------------------------------------------------
__global__ __launch_bounds__(256) void w_prep(
    const float* __restrict__ W, unsigned short* __restrict__ wt)
{
    int idx = blockIdx.x * 256 + threadIdx.x;   // 0..16383
    int k = idx >> 7, n = idx & 127;
    wt[(size_t)n * D + k] = f2bf(W[idx]);
}

// ---------------------------------------------------------------------------
// Mega kernel, block-specialized (R11-proven):
//   blocks [0, BUILD_BLOCKS): edge linked-list build (grid-stride)
//   blocks [BUILD_BLOCKS, ...): MFMA GEMM tile
// ---------------------------------------------------------------------------
__global__ __launch_bounds__(256, 4) void mega(
    const float* __restrict__ x, const unsigned short* __restrict__ wt,
    unsigned short* __restrict__ sup,
    const int* __restrict__ row, const int* __restrict__ col,
    const float* __restrict__ ew,
    int* __restrict__ head, int4* __restrict__ entries)
{
    __shared__ unsigned short xs[BM * LDK];      // 34.0 KB

    const int tid = threadIdx.x;

    if (blockIdx.x < BUILD_BLOCKS) {
        for (int e = blockIdx.x * 256 + tid; e < N_EDGES; e += BUILD_BLOCKS * 256) {
            int nx = atomicExch(&head[row[e]], e);
            entries[e] = make_int4(nx, col[e], __float_as_int(ew[e]), 0);
        }
        return;
    }

    // ---- GEMM path
    const int brow = (blockIdx.x - BUILD_BLOCKS) * BM;

    {
        const float4* xv = reinterpret_cast<const float4*>(x);
        #pragma unroll
        for (int i = 0; i < 16; ++i) {
            int idx = tid + i * 256;             // 0..4095
            int r = idx >> 5, k4 = idx & 31;
            int gr = brow + r;
            float4 v = (gr < N_NODES) ? xv[(size_t)gr * D4 + k4]
                                      : make_float4(0.f, 0.f, 0.f, 0.f);
            ushort4 p;
            p.x = f2bf(v.x); p.y = f2bf(v.y); p.z = f2bf(v.z); p.w = f2bf(v.w);
            *reinterpret_cast<ushort4*>(&xs[r * LDK + k4 * 4]) = p;
        }
    }
    __syncthreads();

    const int wave = tid >> 6;
    const int lane = tid & 63;
    const int l15  = lane & 15;
    const int lkg  = lane >> 4;                  // 0..3

    floatx4 acc[2][8];
    #pragma unroll
    for (int m = 0; m < 2; ++m)
        #pragma unroll
        for (int n = 0; n < 8; ++n) acc[m][n] = (floatx4){0.f, 0.f, 0.f, 0.f};

    const short8* bv = reinterpret_cast<const short8*>(wt);
    const int wrow = wave * 32;
    #pragma unroll
    for (int kk = 0; kk < 4; ++kk) {
        int kb = kk * 32 + lkg * 8;
        short8 a0 = *reinterpret_cast<const short8*>(&xs[(wrow + l15) * LDK + kb]);
        short8 a1 = *reinterpret_cast<const short8*>(&xs[(wrow + 16 + l15) * LDK + kb]);
        #pragma unroll
        for (int n = 0; n < 8; ++n) {
            short8 b = bv[(n * 16 + l15) * 16 + kk * 4 + lkg];
            acc[0][n] = __builtin_amdgcn_mfma_f32_16x16x32_bf16(a0, b, acc[0][n], 0, 0, 0);
            acc[1][n] = __builtin_amdgcn_mfma_f32_16x16x32_bf16(a1, b, acc[1][n], 0, 0, 0);
        }
    }

    const int rbase = brow + wrow + lkg * 4;
    #pragma unroll
    for (int m = 0; m < 2; ++m) {
        #pragma unroll
        for (int r = 0; r < 4; ++r) {
            int grow = rbase + m * 16 + r;
            if (grow < N_NODES) {
                #pragma unroll
                for (int n = 0; n < 8; ++n)
                    sup[(size_t)grow * D + n * 16 + l15] = f2bf(acc[m][n][r]);
            }
        }
    }
}

// ---------------------------------------------------------------------------
// Gather: each half-wave owns EIGHT nodes' chains, interleaved -> 8
// independent pointer-chases in flight. Dead chains read entries[0]
// (cache-hot dummy) with weight forced to 0.
// ---------------------------------------------------------------------------
#define GB_NODES 64                              // nodes per block (8 halves x 8)
#define GATHER_BLOCKS ((N_NODES + GB_NODES - 1) / GB_NODES)   // 1563

__global__ __launch_bounds__(256) void gather_list(
    const int* __restrict__ head, const int4* __restrict__ entries,
    const unsigned short* __restrict__ sup, float* __restrict__ out)
{
    const int half = threadIdx.x >> 5;          // 0..7
    const int lane = threadIdx.x & 31;
    const int nb = blockIdx.x * GB_NODES + half * 8;

    float4 a0 = {0.f, 0.f, 0.f, 0.f};
    float4 a1 = a0, a2 = a0, a3 = a0, a4 = a0, a5 = a0, a6 = a0, a7 = a0;

    int e0 = (nb + 0 < N_NODES) ? head[nb + 0] : -1;
    int e1 = (nb + 1 < N_NODES) ? head[nb + 1] : -1;
    int e2 = (nb + 2 < N_NODES) ? head[nb + 2] : -1;
    int e3 = (nb + 3 < N_NODES) ? head[nb + 3] : -1;
    int e4 = (nb + 4 < N_NODES) ? head[nb + 4] : -1;
    int e5 = (nb + 5 < N_NODES) ? head[nb + 5] : -1;
    int e6 = (nb + 6 < N_NODES) ? head[nb + 6] : -1;
    int e7 = (nb + 7 < N_NODES) ? head[nb + 7] : -1;

    while ((e0 | e1 | e2 | e3 | e4 | e5 | e6 | e7) != -1 ||
           (e0 >= 0 || e1 >= 0 || e2 >= 0 || e3 >= 0 ||
            e4 >= 0 || e5 >= 0 || e6 >= 0 || e7 >= 0)) {
        int4 q0 = entries[e0 >= 0 ? e0 : 0];
        int4 q1 = entries[e1 >= 0 ? e1 : 0];
        int4 q2 = entries[e2 >= 0 ? e2 : 0];
        int4 q3 = entries[e3 >= 0 ? e3 : 0];
        int4 q4 = entries[e4 >= 0 ? e4 : 0];
        int4 q5 = entries[e5 >= 0 ? e5 : 0];
        int4 q6 = entries[e6 >= 0 ? e6 : 0];
        int4 q7 = entries[e7 >= 0 ? e7 : 0];

        ushort4 s0 = reinterpret_cast<const ushort4*>(sup + (size_t)q0.y * D)[lane];
        ushort4 s1 = reinterpret_cast<const ushort4*>(sup + (size_t)q1.y * D)[lane];
        ushort4 s2 = reinterpret_cast<const ushort4*>(sup + (size_t)q2.y * D)[lane];
        ushort4 s3 = reinterpret_cast<const ushort4*>(sup + (size_t)q3.y * D)[lane];
        ushort4 s4 = reinterpret_cast<const ushort4*>(sup + (size_t)q4.y * D)[lane];
        ushort4 s5 = reinterpret_cast<const ushort4*>(sup + (size_t)q5.y * D)[lane];
        ushort4 s6 = reinterpret_cast<const ushort4*>(sup + (size_t)q6.y * D)[lane];
        ushort4 s7 = reinterpret_cast<const ushort4*>(sup + (size_t)q7.y * D)[lane];

        float w0 = (e0 >= 0) ? __int_as_float(q0.z) : 0.f;
        float w1 = (e1 >= 0) ? __int_as_float(q1.z) : 0.f;
        float w2 = (e2 >= 0) ? __int_as_float(q2.z) : 0.f;
        float w3 = (e3 >= 0) ? __int_as_float(q3.z) : 0.f;
        float w4 = (e4 >= 0) ? __int_as_float(q4.z) : 0.f;
        float w5 = (e5 >= 0) ? __int_as_float(q5.z) : 0.f;
        float w6 = (e6 >= 0) ? __int_as_float(q6.z) : 0.f;
        float w7 = (e7 >= 0) ? __int_as_float(q7.z) : 0.f;

        a0.x = fmaf(w0, bf2f(s0.x), a0.x); a0.y = fmaf(w0, bf2f(s0.y), a0.y);
        a0.z = fmaf(w0, bf2f(s0.z), a0.z); a0.w = fmaf(w0, bf2f(s0.w), a0.w);
        a1.x = fmaf(w1, bf2f(s1.x), a1.x); a1.y = fmaf(w1, bf2f(s1.y), a1.y);
        a1.z = fmaf(w1, bf2f(s1.z), a1.z); a1.w = fmaf(w1, bf2f(s1.w), a1.w);
        a2.x = fmaf(w2, bf2f(s2.x), a2.x); a2.y = fmaf(w2, bf2f(s2.y), a2.y);
        a2.z = fmaf(w2, bf2f(s2.z), a2.z); a2.w = fmaf(w2, bf2f(s2.w), a2.w);
        a3.x = fmaf(w3, bf2f(s3.x), a3.x); a3.y = fmaf(w3, bf2f(s3.y), a3.y);
        a3.z = fmaf(w3, bf2f(s3.z), a3.z); a3.w = fmaf(w3, bf2f(s3.w), a3.w);
        a4.x = fmaf(w4, bf2f(s4.x), a4.x); a4.y = fmaf(w4, bf2f(s4.y), a4.y);
        a4.z = fmaf(w4, bf2f(s4.z), a4.z); a4.w = fmaf(w4, bf2f(s4.w), a4.w);
        a5.x = fmaf(w5, bf2f(s5.x), a5.x); a5.y = fmaf(w5, bf2f(s5.y), a5.y);
        a5.z = fmaf(w5, bf2f(s5.z), a5.z); a5.w = fmaf(w5, bf2f(s5.w), a5.w);
        a6.x = fmaf(w6, bf2f(s6.x), a6.x); a6.y = fmaf(w6, bf2f(s6.y), a6.y);
        a6.z = fmaf(w6, bf2f(s6.z), a6.z); a6.w = fmaf(w6, bf2f(s6.w), a6.w);
        a7.x = fmaf(w7, bf2f(s7.x), a7.x); a7.y = fmaf(w7, bf2f(s7.y), a7.y);
        a7.z = fmaf(w7, bf2f(s7.z), a7.z); a7.w = fmaf(w7, bf2f(s7.w), a7.w);

        e0 = (e0 >= 0) ? q0.x : -1;
        e1 = (e1 >= 0) ? q1.x : -1;
        e2 = (e2 >= 0) ? q2.x : -1;
        e3 = (e3 >= 0) ? q3.x : -1;
        e4 = (e4 >= 0) ? q4.x : -1;
        e5 = (e5 >= 0) ? q5.x : -1;
        e6 = (e6 >= 0) ? q6.x : -1;
        e7 = (e7 >= 0) ? q7.x : -1;
    }

    float4* ov = reinterpret_cast<float4*>(out);
    if (nb + 0 < N_NODES) ov[(size_t)(nb + 0) * D4 + lane] = a0;
    if (nb + 1 < N_NODES) ov[(size_t)(nb + 1) * D4 + lane] = a1;
    if (nb + 2 < N_NODES) ov[(size_t)(nb + 2) * D4 + lane] = a2;
    if (nb + 3 < N_NODES) ov[(size_t)(nb + 3) * D4 + lane] = a3;
    if (nb + 4 < N_NODES) ov[(size_t)(nb + 4) * D4 + lane] = a4;
    if (nb + 5 < N_NODES) ov[(size_t)(nb + 5) * D4 + lane] = a5;
    if (nb + 6 < N_NODES) ov[(size_t)(nb + 6) * D4 + lane] = a6;
    if (nb + 7 < N_NODES) ov[(size_t)(nb + 7) * D4 + lane] = a7;
}

// ---------------------------------------------------------------------------
// Fallback path (ws too small): VALU gemm + atomic scatter (proven R3/R8).
// ---------------------------------------------------------------------------
__device__ __forceinline__ void fma4(float4& a, float s, const float4& b) {
    a.x = fmaf(s, b.x, a.x);
    a.y = fmaf(s, b.y, a.y);
    a.z = fmaf(s, b.z, a.z);
    a.w = fmaf(s, b.w, a.w);
}

__global__ __launch_bounds__(256) void gemm_xw(
    const float* __restrict__ x, const float* __restrict__ W,
    unsigned short* __restrict__ sup)
{
    __shared__ float4 xs[32 * D4];
    const int tid = threadIdx.x;
    const int block_row = blockIdx.x * 32;

    const float4* xv = reinterpret_cast<const float4*>(x) + (size_t)block_row * D4;
    #pragma unroll
    for (int i = 0; i < 4; ++i) xs[tid + i * 256] = xv[tid + i * 256];
    __syncthreads();

    const int cg = tid & 31;
    const int rg = tid >> 5;
    const float4* Wv = reinterpret_cast<const float4*>(W);

    float4 acc0 = {0.f, 0.f, 0.f, 0.f};
    float4 acc1 = acc0, acc2 = acc0, acc3 = acc0;

    const int r0 = rg * 4;
    #pragma unroll 8
    for (int k4 = 0; k4 < D4; ++k4) {
        float4 xa = xs[(r0 + 0) * D4 + k4];
        float4 xb = xs[(r0 + 1) * D4 + k4];
        float4 xc = xs[(r0 + 2) * D4 + k4];
        float4 xd = xs[(r0 + 3) * D4 + k4];
        float4 w0 = Wv[(k4 * 4 + 0) * D4 + cg];
        fma4(acc0, xa.x, w0); fma4(acc1, xb.x, w0);
        fma4(acc2, xc.x, w0); fma4(acc3, xd.x, w0);
        float4 w1 = Wv[(k4 * 4 + 1) * D4 + cg];
        fma4(acc0, xa.y, w1); fma4(acc1, xb.y, w1);
        fma4(acc2, xc.y, w1); fma4(acc3, xd.y, w1);
        float4 w2 = Wv[(k4 * 4 + 2) * D4 + cg];
        fma4(acc0, xa.z, w2); fma4(acc1, xb.z, w2);
        fma4(acc2, xc.z, w2); fma4(acc3, xd.z, w2);
        float4 w3 = Wv[(k4 * 4 + 3) * D4 + cg];
        fma4(acc0, xa.w, w3); fma4(acc1, xb.w, w3);
        fma4(acc2, xc.w, w3); fma4(acc3, xd.w, w3);
    }

    ushort4 p;
    #define STORE_BF16(ACC, R)                                            \
        p.x = f2bf(ACC.x); p.y = f2bf(ACC.y);                             \
        p.z = f2bf(ACC.z); p.w = f2bf(ACC.w);                             \
        *reinterpret_cast<ushort4*>(sup + (size_t)(block_row + r0 + R) * D + cg * 4) = p;
    STORE_BF16(acc0, 0)
    STORE_BF16(acc1, 1)
    STORE_BF16(acc2, 2)
    STORE_BF16(acc3, 3)
    #undef STORE_BF16
}

__global__ __launch_bounds__(256) void scatter_edges(
    const int* __restrict__ row, const int* __restrict__ col,
    const float* __restrict__ ew, const unsigned short* __restrict__ sup,
    float* __restrict__ out)
{
    const int e = blockIdx.x * 8 + (threadIdx.x >> 5);
    if (e >= N_EDGES) return;
    const int lane = threadIdx.x & 31;

    const int r = row[e];
    const int c = col[e];
    const float w = ew[e];
    ushort4 s = reinterpret_cast<const ushort4*>(sup + (size_t)c * D)[lane];
    float* o = out + (size_t)r * D + lane * 4;
    atomicAdd(o + 0, w * bf2f(s.x));
    atomicAdd(o + 1, w * bf2f(s.y));
    atomicAdd(o + 2, w * bf2f(s.z));
    atomicAdd(o + 3, w * bf2f(s.w));
}

extern "C" void kernel_launch(void* const* d_in, const int* in_sizes, int n_in,
                              void* d_out, int out_size, void* d_ws, size_t ws_size,
                              hipStream_t stream)
{
    const float* x      = (const float*)d_in[0];   // [N_NODES, 128]
    const int*   row    = (const int*)d_in[1];     // [N_EDGES]
    const int*   col    = (const int*)d_in[2];     // [N_EDGES]
    const float* ew     = (const float*)d_in[3];   // [N_EDGES]
    const float* weight = (const float*)d_in[4];   // [128, 128]
    float* out = (float*)d_out;                    // [N_NODES, 128]

    char* ws = (char*)d_ws;
    const size_t off_sup     = 0;                                      // 25.6 MB
    const size_t off_head    = off_sup + (size_t)N_NODES * D * 2;      // 400 KB
    const size_t off_entries = off_head + (((size_t)N_NODES * 4 + 15) & ~(size_t)15);
    const size_t off_wt      = off_entries + (size_t)N_EDGES * 16;     // 32 KB
    const size_t required    = off_wt + (size_t)D * D * 2;

    unsigned short* sup = (unsigned short*)(ws + off_sup);

    if (ws_size >= required) {
        int*  head    = (int*)(ws + off_head);
        int4* entries = (int4*)(ws + off_entries);
        unsigned short* wt = (unsigned short*)(ws + off_wt);

        hipMemsetAsync(head, 0xFF, (size_t)N_NODES * 4, stream);       // head = -1
        w_prep<<<D * D / 256, 256, 0, stream>>>(weight, wt);

        // block-specialized: builders (first) + MFMA gemm tiles, overlapped
        mega<<<TOTAL_BLOCKS, 256, 0, stream>>>(
            x, wt, sup, row, col, ew, head, entries);

        // gather: writes every output row (no out memset needed)
        gather_list<<<GATHER_BLOCKS, 256, 0, stream>>>(head, entries, sup, out);
    } else {
        gemm_xw<<<N_NODES / 32, 256, 0, stream>>>(x, weight, sup);
        hipMemsetAsync(d_out, 0, (size_t)N_NODES * D * sizeof(float), stream);
        scatter_edges<<<N_EDGES / 8, 256, 0, stream>>>(row, col, ew, sup, out);
    }
}

// Round 14
// 190.452 us; speedup vs baseline: 1.3243x; 1.0260x over previous
//
#include <hip/hip_runtime.h>

#define N_NODES 100000
#define N_EDGES 1600000
#define D 128           // D_IN == D_OUT == 128
#define D4 32           // D in float4 units

#define BM 128                                   // gemm rows per block
#define GEMM_BLOCKS ((N_NODES + BM - 1) / BM)    // 782
#define BUILD_BLOCKS 256                         // edge-list builder blocks
#define TOTAL_BLOCKS (BUILD_BLOCKS + GEMM_BLOCKS)
#define LDK 136                                  // padded LDS row (bf16 elems)

typedef __attribute__((ext_vector_type(8))) short short8;   // MFMA A/B frag
typedef __attribute__((ext_vector_type(4))) float floatx4;  // MFMA C/D frag

// ---- bf16 helpers ----------------------------------------------------------
__device__ __forceinline__ unsigned short f2bf(float f) {
    unsigned int b = __float_as_uint(f);
    b += 0x7FFFu + ((b >> 16) & 1u);           // RNE
    return (unsigned short)(b >> 16);
}
__device__ __forceinline__ float bf2f(unsigned short u) {
    return __uint_as_float((unsigned int)u << 16);
}

// ---------------------------------------------------------------------------
// W^T prep (once): wt[n*128+k] = bf16(W[k*128+n]).
// ---------------------------------------------------------------------------
__global__ __launch_bounds__(256) void w_prep(
    const float* __restrict__ W, unsigned short* __restrict__ wt)
{
    int idx = blockIdx.x * 256 + threadIdx.x;   // 0..16383
    int k = idx >> 7, n = idx & 127;
    wt[(size_t)n * D + k] = f2bf(W[idx]);
}

// ---------------------------------------------------------------------------
// Mega kernel, block-specialized (R11-proven):
//   blocks [0, BUILD_BLOCKS): edge list build, TWO sub-chains per node
//     (head[(row<<1) | (e&1)]) -> 200K heads, mean length ~8.
//   blocks [BUILD_BLOCKS, ...): MFMA GEMM tile.
// ---------------------------------------------------------------------------
__global__ __launch_bounds__(256, 4) void mega(
    const float* __restrict__ x, const unsigned short* __restrict__ wt,
    unsigned short* __restrict__ sup,
    const int* __restrict__ row, const int* __restrict__ col,
    const float* __restrict__ ew,
    int* __restrict__ head, int4* __restrict__ entries)
{
    __shared__ unsigned short xs[BM * LDK];      // 34.0 KB

    const int tid = threadIdx.x;

    if (blockIdx.x < BUILD_BLOCKS) {
        const int S = BUILD_BLOCKS * 256;        // 65536 (even -> e&1 const/thread)
        int e = blockIdx.x * 256 + tid;
        const int par = e & 1;
        // unroll x4: 4 independent atomicExch in flight
        for (; e + 3 * S < N_EDGES; e += 4 * S) {
            int r0 = row[e], r1 = row[e + S], r2 = row[e + 2 * S], r3 = row[e + 3 * S];
            int c0 = col[e], c1 = col[e + S], c2 = col[e + 2 * S], c3 = col[e + 3 * S];
            float w0 = ew[e], w1 = ew[e + S], w2 = ew[e + 2 * S], w3 = ew[e + 3 * S];
            int n0 = atomicExch(&head[(r0 << 1) | par], e);
            int n1 = atomicExch(&head[(r1 << 1) | par], e + S);
            int n2 = atomicExch(&head[(r2 << 1) | par], e + 2 * S);
            int n3 = atomicExch(&head[(r3 << 1) | par], e + 3 * S);
            entries[e]         = make_int4(n0, c0, __float_as_int(w0), 0);
            entries[e + S]     = make_int4(n1, c1, __float_as_int(w1), 0);
            entries[e + 2 * S] = make_int4(n2, c2, __float_as_int(w2), 0);
            entries[e + 3 * S] = make_int4(n3, c3, __float_as_int(w3), 0);
        }
        for (; e < N_EDGES; e += S) {
            int nx = atomicExch(&head[(row[e] << 1) | par], e);
            entries[e] = make_int4(nx, col[e], __float_as_int(ew[e]), 0);
        }
        return;
    }

    // ---- GEMM path
    const int brow = (blockIdx.x - BUILD_BLOCKS) * BM;

    {
        const float4* xv = reinterpret_cast<const float4*>(x);
        #pragma unroll
        for (int i = 0; i < 16; ++i) {
            int idx = tid + i * 256;             // 0..4095
            int r = idx >> 5, k4 = idx & 31;
            int gr = brow + r;
            float4 v = (gr < N_NODES) ? xv[(size_t)gr * D4 + k4]
                                      : make_float4(0.f, 0.f, 0.f, 0.f);
            ushort4 p;
            p.x = f2bf(v.x); p.y = f2bf(v.y); p.z = f2bf(v.z); p.w = f2bf(v.w);
            *reinterpret_cast<ushort4*>(&xs[r * LDK + k4 * 4]) = p;
        }
    }
    __syncthreads();

    const int wave = tid >> 6;
    const int lane = tid & 63;
    const int l15  = lane & 15;
    const int lkg  = lane >> 4;                  // 0..3

    floatx4 acc[2][8];
    #pragma unroll
    for (int m = 0; m < 2; ++m)
        #pragma unroll
        for (int n = 0; n < 8; ++n) acc[m][n] = (floatx4){0.f, 0.f, 0.f, 0.f};

    const short8* bv = reinterpret_cast<const short8*>(wt);
    const int wrow = wave * 32;
    #pragma unroll
    for (int kk = 0; kk < 4; ++kk) {
        int kb = kk * 32 + lkg * 8;
        short8 a0 = *reinterpret_cast<const short8*>(&xs[(wrow + l15) * LDK + kb]);
        short8 a1 = *reinterpret_cast<const short8*>(&xs[(wrow + 16 + l15) * LDK + kb]);
        #pragma unroll
        for (int n = 0; n < 8; ++n) {
            short8 b = bv[(n * 16 + l15) * 16 + kk * 4 + lkg];
            acc[0][n] = __builtin_amdgcn_mfma_f32_16x16x32_bf16(a0, b, acc[0][n], 0, 0, 0);
            acc[1][n] = __builtin_amdgcn_mfma_f32_16x16x32_bf16(a1, b, acc[1][n], 0, 0, 0);
        }
    }

    const int rbase = brow + wrow + lkg * 4;
    #pragma unroll
    for (int m = 0; m < 2; ++m) {
        #pragma unroll
        for (int r = 0; r < 4; ++r) {
            int grow = rbase + m * 16 + r;
            if (grow < N_NODES) {
                #pragma unroll
                for (int n = 0; n < 8; ++n)
                    sup[(size_t)grow * D + n * 16 + l15] = f2bf(acc[m][n][r]);
            }
        }
    }
}

// ---------------------------------------------------------------------------
// Gather: half-wave (32 lanes) owns 2 nodes = 4 sub-chains, interleaved ->
// 4 independent pointer-chases in flight, chains half as long, grid 2x R11
// (6250 blocks = 25000 waves, fills the machine). Heads contiguous: int4.
// ---------------------------------------------------------------------------
#define GATHER_BLOCKS (N_NODES / 16)             // 6250 exact

__global__ __launch_bounds__(256) void gather_list(
    const int* __restrict__ head, const int4* __restrict__ entries,
    const unsigned short* __restrict__ sup, float* __restrict__ out)
{
    const int half = threadIdx.x >> 5;          // 0..7
    const int lane = threadIdx.x & 31;
    const int nb = blockIdx.x * 16 + half * 2;  // 2 nodes per half-wave

    // 4 sub-chain heads, contiguous in memory
    int4 h = *reinterpret_cast<const int4*>(head + 2 * nb);
    int e0 = h.x, e1 = h.y, e2 = h.z, e3 = h.w;

    float4 A0 = {0.f, 0.f, 0.f, 0.f};
    float4 A1 = A0, A2 = A0, A3 = A0;

    while (e0 >= 0 || e1 >= 0 || e2 >= 0 || e3 >= 0) {
        int4 q0 = entries[e0 >= 0 ? e0 : 0];
        int4 q1 = entries[e1 >= 0 ? e1 : 0];
        int4 q2 = entries[e2 >= 0 ? e2 : 0];
        int4 q3 = entries[e3 >= 0 ? e3 : 0];

        ushort4 s0 = reinterpret_cast<const ushort4*>(sup + (size_t)q0.y * D)[lane];
        ushort4 s1 = reinterpret_cast<const ushort4*>(sup + (size_t)q1.y * D)[lane];
        ushort4 s2 = reinterpret_cast<const ushort4*>(sup + (size_t)q2.y * D)[lane];
        ushort4 s3 = reinterpret_cast<const ushort4*>(sup + (size_t)q3.y * D)[lane];

        float w0 = (e0 >= 0) ? __int_as_float(q0.z) : 0.f;
        float w1 = (e1 >= 0) ? __int_as_float(q1.z) : 0.f;
        float w2 = (e2 >= 0) ? __int_as_float(q2.z) : 0.f;
        float w3 = (e3 >= 0) ? __int_as_float(q3.z) : 0.f;

        A0.x = fmaf(w0, bf2f(s0.x), A0.x); A0.y = fmaf(w0, bf2f(s0.y), A0.y);
        A0.z = fmaf(w0, bf2f(s0.z), A0.z); A0.w = fmaf(w0, bf2f(s0.w), A0.w);
        A1.x = fmaf(w1, bf2f(s1.x), A1.x); A1.y = fmaf(w1, bf2f(s1.y), A1.y);
        A1.z = fmaf(w1, bf2f(s1.z), A1.z); A1.w = fmaf(w1, bf2f(s1.w), A1.w);
        A2.x = fmaf(w2, bf2f(s2.x), A2.x); A2.y = fmaf(w2, bf2f(s2.y), A2.y);
        A2.z = fmaf(w2, bf2f(s2.z), A2.z); A2.w = fmaf(w2, bf2f(s2.w), A2.w);
        A3.x = fmaf(w3, bf2f(s3.x), A3.x); A3.y = fmaf(w3, bf2f(s3.y), A3.y);
        A3.z = fmaf(w3, bf2f(s3.z), A3.z); A3.w = fmaf(w3, bf2f(s3.w), A3.w);

        e0 = (e0 >= 0) ? q0.x : -1;
        e1 = (e1 >= 0) ? q1.x : -1;
        e2 = (e2 >= 0) ? q2.x : -1;
        e3 = (e3 >= 0) ? q3.x : -1;
    }

    float4 a0, a1;
    a0.x = A0.x + A1.x; a0.y = A0.y + A1.y; a0.z = A0.z + A1.z; a0.w = A0.w + A1.w;
    a1.x = A2.x + A3.x; a1.y = A2.y + A3.y; a1.z = A2.z + A3.z; a1.w = A2.w + A3.w;

    float4* ov = reinterpret_cast<float4*>(out);
    ov[(size_t)(nb + 0) * D4 + lane] = a0;
    ov[(size_t)(nb + 1) * D4 + lane] = a1;
}

// ---------------------------------------------------------------------------
// Fallback path (ws too small): VALU gemm + atomic scatter (proven R3/R8).
// ---------------------------------------------------------------------------
__device__ __forceinline__ void fma4(float4& a, float s, const float4& b) {
    a.x = fmaf(s, b.x, a.x);
    a.y = fmaf(s, b.y, a.y);
    a.z = fmaf(s, b.z, a.z);
    a.w = fmaf(s, b.w, a.w);
}

__global__ __launch_bounds__(256) void gemm_xw(
    const float* __restrict__ x, const float* __restrict__ W,
    unsigned short* __restrict__ sup)
{
    __shared__ float4 xs[32 * D4];
    const int tid = threadIdx.x;
    const int block_row = blockIdx.x * 32;

    const float4* xv = reinterpret_cast<const float4*>(x) + (size_t)block_row * D4;
    #pragma unroll
    for (int i = 0; i < 4; ++i) xs[tid + i * 256] = xv[tid + i * 256];
    __syncthreads();

    const int cg = tid & 31;
    const int rg = tid >> 5;
    const float4* Wv = reinterpret_cast<const float4*>(W);

    float4 acc0 = {0.f, 0.f, 0.f, 0.f};
    float4 acc1 = acc0, acc2 = acc0, acc3 = acc0;

    const int r0 = rg * 4;
    #pragma unroll 8
    for (int k4 = 0; k4 < D4; ++k4) {
        float4 xa = xs[(r0 + 0) * D4 + k4];
        float4 xb = xs[(r0 + 1) * D4 + k4];
        float4 xc = xs[(r0 + 2) * D4 + k4];
        float4 xd = xs[(r0 + 3) * D4 + k4];
        float4 w0 = Wv[(k4 * 4 + 0) * D4 + cg];
        fma4(acc0, xa.x, w0); fma4(acc1, xb.x, w0);
        fma4(acc2, xc.x, w0); fma4(acc3, xd.x, w0);
        float4 w1 = Wv[(k4 * 4 + 1) * D4 + cg];
        fma4(acc0, xa.y, w1); fma4(acc1, xb.y, w1);
        fma4(acc2, xc.y, w1); fma4(acc3, xd.y, w1);
        float4 w2 = Wv[(k4 * 4 + 2) * D4 + cg];
        fma4(acc0, xa.z, w2); fma4(acc1, xb.z, w2);
        fma4(acc2, xc.z, w2); fma4(acc3, xd.z, w2);
        float4 w3 = Wv[(k4 * 4 + 3) * D4 + cg];
        fma4(acc0, xa.w, w3); fma4(acc1, xb.w, w3);
        fma4(acc2, xc.w, w3); fma4(acc3, xd.w, w3);
    }

    ushort4 p;
    #define STORE_BF16(ACC, R)                                            \
        p.x = f2bf(ACC.x); p.y = f2bf(ACC.y);                             \
        p.z = f2bf(ACC.z); p.w = f2bf(ACC.w);                             \
        *reinterpret_cast<ushort4*>(sup + (size_t)(block_row + r0 + R) * D + cg * 4) = p;
    STORE_BF16(acc0, 0)
    STORE_BF16(acc1, 1)
    STORE_BF16(acc2, 2)
    STORE_BF16(acc3, 3)
    #undef STORE_BF16
}

__global__ __launch_bounds__(256) void scatter_edges(
    const int* __restrict__ row, const int* __restrict__ col,
    const float* __restrict__ ew, const unsigned short* __restrict__ sup,
    float* __restrict__ out)
{
    const int e = blockIdx.x * 8 + (threadIdx.x >> 5);
    if (e >= N_EDGES) return;
    const int lane = threadIdx.x & 31;

    const int r = row[e];
    const int c = col[e];
    const float w = ew[e];
    ushort4 s = reinterpret_cast<const ushort4*>(sup + (size_t)c * D)[lane];
    float* o = out + (size_t)r * D + lane * 4;
    atomicAdd(o + 0, w * bf2f(s.x));
    atomicAdd(o + 1, w * bf2f(s.y));
    atomicAdd(o + 2, w * bf2f(s.z));
    atomicAdd(o + 3, w * bf2f(s.w));
}

extern "C" void kernel_launch(void* const* d_in, const int* in_sizes, int n_in,
                              void* d_out, int out_size, void* d_ws, size_t ws_size,
                              hipStream_t stream)
{
    const float* x      = (const float*)d_in[0];   // [N_NODES, 128]
    const int*   row    = (const int*)d_in[1];     // [N_EDGES]
    const int*   col    = (const int*)d_in[2];     // [N_EDGES]
    const float* ew     = (const float*)d_in[3];   // [N_EDGES]
    const float* weight = (const float*)d_in[4];   // [128, 128]
    float* out = (float*)d_out;                    // [N_NODES, 128]

    char* ws = (char*)d_ws;
    const size_t off_sup     = 0;                                      // 25.6 MB
    const size_t off_head    = off_sup + (size_t)N_NODES * D * 2;      // 800 KB (2 chains/node)
    const size_t off_entries = off_head + (((size_t)N_NODES * 8 + 15) & ~(size_t)15);
    const size_t off_wt      = off_entries + (size_t)N_EDGES * 16;     // 32 KB
    const size_t required    = off_wt + (size_t)D * D * 2;

    unsigned short* sup = (unsigned short*)(ws + off_sup);

    if (ws_size >= required) {
        int*  head    = (int*)(ws + off_head);
        int4* entries = (int4*)(ws + off_entries);
        unsigned short* wt = (unsigned short*)(ws + off_wt);

        hipMemsetAsync(head, 0xFF, (size_t)N_NODES * 8, stream);       // head = -1
        w_prep<<<D * D / 256, 256, 0, stream>>>(weight, wt);

        // block-specialized: builders (first) + MFMA gemm tiles, overlapped
        mega<<<TOTAL_BLOCKS, 256, 0, stream>>>(
            x, wt, sup, row, col, ew, head, entries);

        // gather: writes every output row (no out memset needed)
        gather_list<<<GATHER_BLOCKS, 256, 0, stream>>>(head, entries, sup, out);
    } else {
        gemm_xw<<<N_NODES / 32, 256, 0, stream>>>(x, weight, sup);
        hipMemsetAsync(d_out, 0, (size_t)N_NODES * D * sizeof(float), stream);
        scatter_edges<<<N_EDGES / 8, 256, 0, stream>>>(row, col, ew, sup, out);
    }
}

// Round 15
// 186.027 us; speedup vs baseline: 1.3558x; 1.0238x over previous
//
#include <hip/hip_runtime.h>

#define N_NODES 100000
#define N_EDGES 1600000
#define D 128           // D_IN == D_OUT == 128
#define D4 32           // D in float4 units

#define BM 128                                   // gemm rows per block
#define GEMM_BLOCKS ((N_NODES + BM - 1) / BM)    // 782
#define BUILD_BLOCKS 512                         // edge-list builder blocks
#define TOTAL_BLOCKS (BUILD_BLOCKS + GEMM_BLOCKS)
#define LDK 136                                  // padded LDS row (bf16 elems)

typedef __attribute__((ext_vector_type(8))) short short8;   // MFMA A/B frag
typedef __attribute__((ext_vector_type(4))) float floatx4;  // MFMA C/D frag

// ---- bf16 helpers ----------------------------------------------------------
__device__ __forceinline__ unsigned short f2bf(float f) {
    unsigned int b = __float_as_uint(f);
    b += 0x7FFFu + ((b >> 16) & 1u);           // RNE
    return (unsigned short)(b >> 16);
}
__device__ __forceinline__ float bf2f(unsigned short u) {
    return __uint_as_float((unsigned int)u << 16);
}

// ---------------------------------------------------------------------------
// W^T prep (once): wt[n*128+k] = bf16(W[k*128+n]).
// ---------------------------------------------------------------------------
__global__ __launch_bounds__(256) void w_prep(
    const float* __restrict__ W, unsigned short* __restrict__ wt)
{
    int idx = blockIdx.x * 256 + threadIdx.x;   // 0..16383
    int k = idx >> 7, n = idx & 127;
    wt[(size_t)n * D + k] = f2bf(W[idx]);
}

// ---------------------------------------------------------------------------
// Mega kernel, block-specialized:
//   blocks [0, BUILD_BLOCKS): edge list build (simple loop, R13-proven),
//     TWO sub-chains per node: head[(row<<1) | (tid&1)] -> 200K heads.
//   blocks [BUILD_BLOCKS, ...): MFMA GEMM tile (R10/R11-proven).
// ---------------------------------------------------------------------------
__global__ __launch_bounds__(256, 4) void mega(
    const float* __restrict__ x, const unsigned short* __restrict__ wt,
    unsigned short* __restrict__ sup,
    const int* __restrict__ row, const int* __restrict__ col,
    const float* __restrict__ ew,
    int* __restrict__ head, int4* __restrict__ entries)
{
    __shared__ unsigned short xs[BM * LDK];      // 34.0 KB

    const int tid = threadIdx.x;

    if (blockIdx.x < BUILD_BLOCKS) {
        const int S = BUILD_BLOCKS * 256;        // 131072 (even -> parity const)
        const int par = tid & 1;
        for (int e = blockIdx.x * 256 + tid; e < N_EDGES; e += S) {
            int nx = atomicExch(&head[(row[e] << 1) | par], e);
            entries[e] = make_int4(nx, col[e], __float_as_int(ew[e]), 0);
        }
        return;
    }

    // ---- GEMM path
    const int brow = (blockIdx.x - BUILD_BLOCKS) * BM;

    {
        const float4* xv = reinterpret_cast<const float4*>(x);
        #pragma unroll
        for (int i = 0; i < 16; ++i) {
            int idx = tid + i * 256;             // 0..4095
            int r = idx >> 5, k4 = idx & 31;
            int gr = brow + r;
            float4 v = (gr < N_NODES) ? xv[(size_t)gr * D4 + k4]
                                      : make_float4(0.f, 0.f, 0.f, 0.f);
            ushort4 p;
            p.x = f2bf(v.x); p.y = f2bf(v.y); p.z = f2bf(v.z); p.w = f2bf(v.w);
            *reinterpret_cast<ushort4*>(&xs[r * LDK + k4 * 4]) = p;
        }
    }
    __syncthreads();

    const int wave = tid >> 6;
    const int lane = tid & 63;
    const int l15  = lane & 15;
    const int lkg  = lane >> 4;                  // 0..3

    floatx4 acc[2][8];
    #pragma unroll
    for (int m = 0; m < 2; ++m)
        #pragma unroll
        for (int n = 0; n < 8; ++n) acc[m][n] = (floatx4){0.f, 0.f, 0.f, 0.f};

    const short8* bv = reinterpret_cast<const short8*>(wt);
    const int wrow = wave * 32;
    #pragma unroll
    for (int kk = 0; kk < 4; ++kk) {
        int kb = kk * 32 + lkg * 8;
        short8 a0 = *reinterpret_cast<const short8*>(&xs[(wrow + l15) * LDK + kb]);
        short8 a1 = *reinterpret_cast<const short8*>(&xs[(wrow + 16 + l15) * LDK + kb]);
        #pragma unroll
        for (int n = 0; n < 8; ++n) {
            short8 b = bv[(n * 16 + l15) * 16 + kk * 4 + lkg];
            acc[0][n] = __builtin_amdgcn_mfma_f32_16x16x32_bf16(a0, b, acc[0][n], 0, 0, 0);
            acc[1][n] = __builtin_amdgcn_mfma_f32_16x16x32_bf16(a1, b, acc[1][n], 0, 0, 0);
        }
    }

    const int rbase = brow + wrow + lkg * 4;
    #pragma unroll
    for (int m = 0; m < 2; ++m) {
        #pragma unroll
        for (int r = 0; r < 4; ++r) {
            int grow = rbase + m * 16 + r;
            if (grow < N_NODES) {
                #pragma unroll
                for (int n = 0; n < 8; ++n)
                    sup[(size_t)grow * D + n * 16 + l15] = f2bf(acc[m][n][r]);
            }
        }
    }
}

// ---------------------------------------------------------------------------
// Gather: half-wave (32 lanes) owns 2 nodes = 4 sub-chains, interleaved ->
// 4 independent pointer-chases in flight, chains ~8 long, 6250 blocks.
// ---------------------------------------------------------------------------
#define GATHER_BLOCKS (N_NODES / 16)             // 6250 exact

__global__ __launch_bounds__(256) void gather_list(
    const int* __restrict__ head, const int4* __restrict__ entries,
    const unsigned short* __restrict__ sup, float* __restrict__ out)
{
    const int half = threadIdx.x >> 5;          // 0..7
    const int lane = threadIdx.x & 31;
    const int nb = blockIdx.x * 16 + half * 2;  // 2 nodes per half-wave

    // 4 sub-chain heads, contiguous in memory
    int4 h = *reinterpret_cast<const int4*>(head + 2 * nb);
    int e0 = h.x, e1 = h.y, e2 = h.z, e3 = h.w;

    float4 A0 = {0.f, 0.f, 0.f, 0.f};
    float4 A1 = A0, A2 = A0, A3 = A0;

    while (e0 >= 0 || e1 >= 0 || e2 >= 0 || e3 >= 0) {
        int4 q0 = entries[e0 >= 0 ? e0 : 0];
        int4 q1 = entries[e1 >= 0 ? e1 : 0];
        int4 q2 = entries[e2 >= 0 ? e2 : 0];
        int4 q3 = entries[e3 >= 0 ? e3 : 0];

        ushort4 s0 = reinterpret_cast<const ushort4*>(sup + (size_t)q0.y * D)[lane];
        ushort4 s1 = reinterpret_cast<const ushort4*>(sup + (size_t)q1.y * D)[lane];
        ushort4 s2 = reinterpret_cast<const ushort4*>(sup + (size_t)q2.y * D)[lane];
        ushort4 s3 = reinterpret_cast<const ushort4*>(sup + (size_t)q3.y * D)[lane];

        float w0 = (e0 >= 0) ? __int_as_float(q0.z) : 0.f;
        float w1 = (e1 >= 0) ? __int_as_float(q1.z) : 0.f;
        float w2 = (e2 >= 0) ? __int_as_float(q2.z) : 0.f;
        float w3 = (e3 >= 0) ? __int_as_float(q3.z) : 0.f;

        A0.x = fmaf(w0, bf2f(s0.x), A0.x); A0.y = fmaf(w0, bf2f(s0.y), A0.y);
        A0.z = fmaf(w0, bf2f(s0.z), A0.z); A0.w = fmaf(w0, bf2f(s0.w), A0.w);
        A1.x = fmaf(w1, bf2f(s1.x), A1.x); A1.y = fmaf(w1, bf2f(s1.y), A1.y);
        A1.z = fmaf(w1, bf2f(s1.z), A1.z); A1.w = fmaf(w1, bf2f(s1.w), A1.w);
        A2.x = fmaf(w2, bf2f(s2.x), A2.x); A2.y = fmaf(w2, bf2f(s2.y), A2.y);
        A2.z = fmaf(w2, bf2f(s2.z), A2.z); A2.w = fmaf(w2, bf2f(s2.w), A2.w);
        A3.x = fmaf(w3, bf2f(s3.x), A3.x); A3.y = fmaf(w3, bf2f(s3.y), A3.y);
        A3.z = fmaf(w3, bf2f(s3.z), A3.z); A3.w = fmaf(w3, bf2f(s3.w), A3.w);

        e0 = (e0 >= 0) ? q0.x : -1;
        e1 = (e1 >= 0) ? q1.x : -1;
        e2 = (e2 >= 0) ? q2.x : -1;
        e3 = (e3 >= 0) ? q3.x : -1;
    }

    float4 a0, a1;
    a0.x = A0.x + A1.x; a0.y = A0.y + A1.y; a0.z = A0.z + A1.z; a0.w = A0.w + A1.w;
    a1.x = A2.x + A3.x; a1.y = A2.y + A3.y; a1.z = A2.z + A3.z; a1.w = A2.w + A3.w;

    float4* ov = reinterpret_cast<float4*>(out);
    ov[(size_t)(nb + 0) * D4 + lane] = a0;
    ov[(size_t)(nb + 1) * D4 + lane] = a1;
}

// ---------------------------------------------------------------------------
// Fallback path (ws too small): VALU gemm + atomic scatter (proven R3/R8).
// ---------------------------------------------------------------------------
__device__ __forceinline__ void fma4(float4& a, float s, const float4& b) {
    a.x = fmaf(s, b.x, a.x);
    a.y = fmaf(s, b.y, a.y);
    a.z = fmaf(s, b.z, a.z);
    a.w = fmaf(s, b.w, a.w);
}

__global__ __launch_bounds__(256) void gemm_xw(
    const float* __restrict__ x, const float* __restrict__ W,
    unsigned short* __restrict__ sup)
{
    __shared__ float4 xs[32 * D4];
    const int tid = threadIdx.x;
    const int block_row = blockIdx.x * 32;

    const float4* xv = reinterpret_cast<const float4*>(x) + (size_t)block_row * D4;
    #pragma unroll
    for (int i = 0; i < 4; ++i) xs[tid + i * 256] = xv[tid + i * 256];
    __syncthreads();

    const int cg = tid & 31;
    const int rg = tid >> 5;
    const float4* Wv = reinterpret_cast<const float4*>(W);

    float4 acc0 = {0.f, 0.f, 0.f, 0.f};
    float4 acc1 = acc0, acc2 = acc0, acc3 = acc0;

    const int r0 = rg * 4;
    #pragma unroll 8
    for (int k4 = 0; k4 < D4; ++k4) {
        float4 xa = xs[(r0 + 0) * D4 + k4];
        float4 xb = xs[(r0 + 1) * D4 + k4];
        float4 xc = xs[(r0 + 2) * D4 + k4];
        float4 xd = xs[(r0 + 3) * D4 + k4];
        float4 w0 = Wv[(k4 * 4 + 0) * D4 + cg];
        fma4(acc0, xa.x, w0); fma4(acc1, xb.x, w0);
        fma4(acc2, xc.x, w0); fma4(acc3, xd.x, w0);
        float4 w1 = Wv[(k4 * 4 + 1) * D4 + cg];
        fma4(acc0, xa.y, w1); fma4(acc1, xb.y, w1);
        fma4(acc2, xc.y, w1); fma4(acc3, xd.y, w1);
        float4 w2 = Wv[(k4 * 4 + 2) * D4 + cg];
        fma4(acc0, xa.z, w2); fma4(acc1, xb.z, w2);
        fma4(acc2, xc.z, w2); fma4(acc3, xd.z, w2);
        float4 w3 = Wv[(k4 * 4 + 3) * D4 + cg];
        fma4(acc0, xa.w, w3); fma4(acc1, xb.w, w3);
        fma4(acc2, xc.w, w3); fma4(acc3, xd.w, w3);
    }

    ushort4 p;
    #define STORE_BF16(ACC, R)                                            \
        p.x = f2bf(ACC.x); p.y = f2bf(ACC.y);                             \
        p.z = f2bf(ACC.z); p.w = f2bf(ACC.w);                             \
        *reinterpret_cast<ushort4*>(sup + (size_t)(block_row + r0 + R) * D + cg * 4) = p;
    STORE_BF16(acc0, 0)
    STORE_BF16(acc1, 1)
    STORE_BF16(acc2, 2)
    STORE_BF16(acc3, 3)
    #undef STORE_BF16
}

__global__ __launch_bounds__(256) void scatter_edges(
    const int* __restrict__ row, const int* __restrict__ col,
    const float* __restrict__ ew, const unsigned short* __restrict__ sup,
    float* __restrict__ out)
{
    const int e = blockIdx.x * 8 + (threadIdx.x >> 5);
    if (e >= N_EDGES) return;
    const int lane = threadIdx.x & 31;

    const int r = row[e];
    const int c = col[e];
    const float w = ew[e];
    ushort4 s = reinterpret_cast<const ushort4*>(sup + (size_t)c * D)[lane];
    float* o = out + (size_t)r * D + lane * 4;
    atomicAdd(o + 0, w * bf2f(s.x));
    atomicAdd(o + 1, w * bf2f(s.y));
    atomicAdd(o + 2, w * bf2f(s.z));
    atomicAdd(o + 3, w * bf2f(s.w));
}

extern "C" void kernel_launch(void* const* d_in, const int* in_sizes, int n_in,
                              void* d_out, int out_size, void* d_ws, size_t ws_size,
                              hipStream_t stream)
{
    const float* x      = (const float*)d_in[0];   // [N_NODES, 128]
    const int*   row    = (const int*)d_in[1];     // [N_EDGES]
    const int*   col    = (const int*)d_in[2];     // [N_EDGES]
    const float* ew     = (const float*)d_in[3];   // [N_EDGES]
    const float* weight = (const float*)d_in[4];   // [128, 128]
    float* out = (float*)d_out;                    // [N_NODES, 128]

    char* ws = (char*)d_ws;
    const size_t off_sup     = 0;                                      // 25.6 MB
    const size_t off_head    = off_sup + (size_t)N_NODES * D * 2;      // 800 KB (2 chains/node)
    const size_t off_entries = off_head + (((size_t)N_NODES * 8 + 15) & ~(size_t)15);
    const size_t off_wt      = off_entries + (size_t)N_EDGES * 16;     // 32 KB
    const size_t required    = off_wt + (size_t)D * D * 2;

    unsigned short* sup = (unsigned short*)(ws + off_sup);

    if (ws_size >= required) {
        int*  head    = (int*)(ws + off_head);
        int4* entries = (int4*)(ws + off_entries);
        unsigned short* wt = (unsigned short*)(ws + off_wt);

        hipMemsetAsync(head, 0xFF, (size_t)N_NODES * 8, stream);       // head = -1
        w_prep<<<D * D / 256, 256, 0, stream>>>(weight, wt);

        // block-specialized: builders (first) + MFMA gemm tiles, overlapped
        mega<<<TOTAL_BLOCKS, 256, 0, stream>>>(
            x, wt, sup, row, col, ew, head, entries);

        // gather: writes every output row (no out memset needed)
        gather_list<<<GATHER_BLOCKS, 256, 0, stream>>>(head, entries, sup, out);
    } else {
        gemm_xw<<<N_NODES / 32, 256, 0, stream>>>(x, weight, sup);
        hipMemsetAsync(d_out, 0, (size_t)N_NODES * D * sizeof(float), stream);
        scatter_edges<<<N_EDGES / 8, 256, 0, stream>>>(row, col, ew, sup, out);
    }
}